// Round 15
// baseline (438.616 us; speedup 1.0000x reference)
//
#include <hip/hip_runtime.h>
#include <hip/hip_bf16.h>

#define N_NODES   50000
#define N_PAD     50048                 // ceil64
#define N_EDGES   800000
#define N_REL     16
#define N_GRAPHS  64
#define DIM       128
#define FC_DIM    256
#define N_CLASSES 16

#define SB        50176                 // src bins per rel (49*1024)
#define NBINS_P   (16 * SB)             // 802816
#define NBLK_PP   784
#define NCOARSE   782                   // dst>>6 bins
#define NCH       98                    // edge chunks
#define CHSZ      8192
#define POOL_CH   64
#define PSTRIDE   782                   // max 64-blocks per rel segment
#define MAXBLK_A  (17 * PSTRIDE)        // 13294

// ---- ws layout (bytes, 256-aligned) ----
#define WS_MARK   0                     // 802816  } contiguous
#define WS_HG     802816                // 32768   } memset
#define WS_CNT    835584                // 256     } region
#define WS_SRCOF  835840                // 3203072 } (pads must be 0)
#define MEMSET_SZ 4038912
#define WS_BLKH   4038912               // 98*782*4 = 306544 -> 306688
#define WS_COFS   4345600               // 3328
#define WS_PARTP  4348928               // 3328
#define WS_BLKB   4352256               // 3328
#define WS_RELB   4355584               // 256
#define WS_CIDMAP 4355840               // 3211264
#define WS_RTMP   7567104               // 3200000
#define WS_RECS   10767104              // 3200000
#define WS_OFFSD  13967104              // 200448
#define WS_X1     14167552              // 12812288
#define WS_X2     26979840              // 12812288
#define WS_AGG    39792128              // 12812288 (bf16)
#define WS_WB     52604416              // 1114112
#define WS_T      53718528              // + rows*256B (actual ~142MB)

#define XW_TOTAL  (N_PAD * DIM + 2 * 17 * 16384)

typedef __attribute__((ext_vector_type(8))) short bf16x8;
typedef __attribute__((ext_vector_type(4))) float f32x4;

__device__ __forceinline__ void atomAddF(float* p, float v) {
#if defined(__gfx90a__) || defined(__gfx942__) || defined(__gfx950__)
    unsafeAtomicAdd(p, v);
#else
    atomicAdd(p, v);
#endif
}

__device__ __forceinline__ float bf2f(unsigned int u) {
    union { float f; unsigned int i; } x; x.i = u << 16; return x.f;
}
__device__ __forceinline__ unsigned short f2bf(float f) {
    union { float f; unsigned int u; } x; x.f = f;
    unsigned int r = x.u + 0x7fff + ((x.u >> 16) & 1);
    return (unsigned short)(r >> 16);
}
__device__ __forceinline__ void accum8(float* qa, uint4 u) {
    qa[0] += bf2f(u.x & 0xffff); qa[1] += bf2f(u.x >> 16);
    qa[2] += bf2f(u.y & 0xffff); qa[3] += bf2f(u.y >> 16);
    qa[4] += bf2f(u.z & 0xffff); qa[5] += bf2f(u.z >> 16);
    qa[6] += bf2f(u.w & 0xffff); qa[7] += bf2f(u.w >> 16);
}
__device__ __forceinline__ void pack16(const float* qa, unsigned short* dst) {
    #pragma unroll
    for (int j = 0; j < 2; ++j) {
        uint4 w;
        w.x = ((unsigned int)f2bf(qa[j*8+1]) << 16) | f2bf(qa[j*8+0]);
        w.y = ((unsigned int)f2bf(qa[j*8+3]) << 16) | f2bf(qa[j*8+2]);
        w.z = ((unsigned int)f2bf(qa[j*8+5]) << 16) | f2bf(qa[j*8+4]);
        w.w = ((unsigned int)f2bf(qa[j*8+7]) << 16) | f2bf(qa[j*8+6]);
        ((uint4*)dst)[j] = w;
    }
}

// merged convX + convW
__global__ void k_convXW(const float* __restrict__ h, unsigned short* __restrict__ x1,
                         const float* __restrict__ W1, const float* __restrict__ Ws1,
                         const float* __restrict__ W2, const float* __restrict__ Ws2,
                         unsigned short* __restrict__ Wb) {
    int id = blockIdx.x * blockDim.x + threadIdx.x;
    if (id < N_PAD * DIM) {
        int v = id >> 7;
        x1[id] = (v < N_NODES) ? f2bf(h[id]) : (unsigned short)0;
    } else {
        int t = id - N_PAD * DIM;
        int l = t / 278528, rem = t % 278528;
        int r = rem >> 14, rr = rem & 16383;
        int n = rr >> 7, k = rr & 127;
        const float* W  = l ? W2 : W1;
        const float* Ws = l ? Ws2 : Ws1;
        float v = (r < 16) ? W[r * 16384 + k * 128 + n] : Ws[k * 128 + n];
        Wb[t] = f2bf(v);
    }
}

// ---- sort pass 1a: per-chunk LDS coarse histogram + dedup marks ----
__global__ __launch_bounds__(256) void k_h1(
    const int* __restrict__ src, const int* __restrict__ dst, const int* __restrict__ rel,
    unsigned char* __restrict__ mark, int* __restrict__ blockHist)
{
    __shared__ int hl[NCOARSE];
    int b = blockIdx.x, t = threadIdx.x;
    for (int i = t; i < NCOARSE; i += 256) hl[i] = 0;
    __syncthreads();
    int e0 = b * CHSZ;
    int eend = min(e0 + CHSZ, N_EDGES);
    for (int e = e0 + t; e < eend; e += 256) {
        int d = dst[e];
        mark[rel[e] * SB + src[e]] = 1;
        atomicAdd(&hl[d >> 6], 1);                       // LDS atomic
    }
    __syncthreads();
    for (int i = t; i < NCOARSE; i += 256) blockHist[b * NCOARSE + i] = hl[i];
}

// ---- fused: block 0 = coarse scan (cscan); block 1 = pair-base scan (scanPB) ----
__global__ __launch_bounds__(1024) void k_scans(
    int* __restrict__ blockHist, int* __restrict__ coarseOffs,
    const int* __restrict__ partP, int* __restrict__ blkB, int* __restrict__ relB)
{
    __shared__ int s1[1024], s2[1024];
    int t = threadIdx.x;
    if (blockIdx.x == 0) {
        int tot = 0;
        if (t < NCOARSE) {
            int run = 0;
            for (int b = 0; b < NCH; ++b) {
                int v = blockHist[b * NCOARSE + t];
                blockHist[b * NCOARSE + t] = run;
                run += v;
            }
            tot = run;
        }
        s1[t] = tot; __syncthreads();
        int* cur = s1; int* nxt = s2;
        for (int o = 1; o < 1024; o <<= 1) {
            nxt[t] = cur[t] + ((t >= o) ? cur[t - o] : 0);
            __syncthreads();
            int* tmp = cur; cur = nxt; nxt = tmp;
        }
        if (t < NCOARSE) {
            int base = cur[t] - tot;
            coarseOffs[t] = base;
            for (int b = 0; b < NCH; ++b) blockHist[b * NCOARSE + t] += base;
        }
        if (t == NCOARSE) coarseOffs[NCOARSE] = cur[NCOARSE - 1];
    } else {
        __shared__ int tot[16], rbase[17];
        int rel = t / 49, pos = t - rel * 49;
        int v = (t < 784) ? partP[t] : 0;
        if (t < 784) s1[t] = v;
        __syncthreads();
        int* cur = s1; int* nxt = s2;
        for (int o = 1; o < 64; o <<= 1) {
            if (t < 784) nxt[t] = cur[t] + ((pos >= o) ? cur[t - o] : 0);
            __syncthreads();
            int* tmp = cur; cur = nxt; nxt = tmp;
        }
        if (t < 784 && pos == 48) tot[rel] = cur[t];
        __syncthreads();
        if (t == 0) {
            int base = 0;
            for (int r = 0; r < 16; ++r) { rbase[r] = base; base += (tot[r] + 63) & ~63; }
            rbase[16] = base;
        }
        __syncthreads();
        if (t < 784) blkB[t] = rbase[rel] + cur[t] - v;
        if (t < 17)  relB[t] = rbase[t];
    }
}

__global__ void k_scanPA(const unsigned int* __restrict__ markU, int* __restrict__ partP) {
    __shared__ int red[256];
    int b = blockIdx.x, t = threadIdx.x;
    unsigned int u = markU[b * 256 + t];
    red[t] = (int)((u & 1) + ((u >> 8) & 1) + ((u >> 16) & 1) + ((u >> 24) & 1));
    __syncthreads();
    for (int o = 128; o > 0; o >>= 1) {
        if (t < o) red[t] += red[t + o];
        __syncthreads();
    }
    if (t == 0) partP[b] = red[0];
}

__global__ void k_scanPC(const unsigned int* __restrict__ markU, const int* __restrict__ blkB,
                         int* __restrict__ cidMap, int* __restrict__ srcOf) {
    __shared__ int s1[256], s2[256];
    int b = blockIdx.x, t = threadIdx.x;
    unsigned int u = markU[b * 256 + t];
    int f0 = (int)(u & 1), f1 = (int)((u >> 8) & 1);
    int f2 = (int)((u >> 16) & 1), f3 = (int)((u >> 24) & 1);
    int sum = f0 + f1 + f2 + f3;
    s1[t] = sum; __syncthreads();
    int* cur = s1; int* nxt = s2;
    for (int o = 1; o < 256; o <<= 1) {
        nxt[t] = cur[t] + ((t >= o) ? cur[t - o] : 0);
        __syncthreads();
        int* tmp = cur; cur = nxt; nxt = tmp;
    }
    int cid = blkB[b] + cur[t] - sum;
    int rel = b / 49;
    int key0 = b * 1024 + t * 4;
    int srcBase = key0 - rel * SB;
    if (f0) { cidMap[key0]     = cid; srcOf[cid] = srcBase;     cid++; }
    if (f1) { cidMap[key0 + 1] = cid; srcOf[cid] = srcBase + 1; cid++; }
    if (f2) { cidMap[key0 + 2] = cid; srcOf[cid] = srcBase + 2; cid++; }
    if (f3) { cidMap[key0 + 3] = cid; srcOf[cid] = srcBase + 3; cid++; }
}

// ---- sort pass 1b: scatter to coarse segments ----
__global__ __launch_bounds__(256) void k_scat1(
    const int* __restrict__ src, const int* __restrict__ dst, const int* __restrict__ rel,
    const int* __restrict__ cidMap, const int* __restrict__ blockHist,
    unsigned int* __restrict__ rtmp)
{
    __shared__ int baseL[NCOARSE];
    __shared__ int hl[NCOARSE];
    int b = blockIdx.x, t = threadIdx.x;
    for (int i = t; i < NCOARSE; i += 256) { baseL[i] = blockHist[b * NCOARSE + i]; hl[i] = 0; }
    __syncthreads();
    int e0 = b * CHSZ;
    int eend = min(e0 + CHSZ, N_EDGES);
    for (int e = e0 + t; e < eend; e += 256) {
        int d = dst[e];
        int cid = cidMap[rel[e] * SB + src[e]];
        int c = d >> 6;
        int rank = atomicAdd(&hl[c], 1);                 // LDS atomic
        rtmp[baseL[c] + rank] = ((unsigned int)cid << 6) | (unsigned int)(d & 63);
    }
}

// ---- sort pass 2: per coarse bin, final 64-way local sort + offsD ----
__global__ __launch_bounds__(256) void k_p2(
    const unsigned int* __restrict__ rtmp, const int* __restrict__ coarseOffs,
    unsigned int* __restrict__ recs, int* __restrict__ offsD)
{
    __shared__ int cntL[64], exclL[65], cur2[64];
    int i = blockIdx.x, t = threadIdx.x;
    int segB = coarseOffs[i], segE = coarseOffs[i + 1];
    if (t < 64) { cntL[t] = 0; cur2[t] = 0; }
    __syncthreads();
    for (int e = segB + t; e < segE; e += 256)
        atomicAdd(&cntL[rtmp[e] & 63u], 1);
    __syncthreads();
    if (t == 0) {
        int run = segB;
        #pragma unroll
        for (int d = 0; d < 64; ++d) { exclL[d] = run; run += cntL[d]; }
        exclL[64] = run;
    }
    __syncthreads();
    if (t < 64) offsD[i * 64 + t] = exclL[t];
    if (t == 64) offsD[i * 64 + 64] = exclL[64];
    for (int e = segB + t; e < segE; e += 256) {
        unsigned int r = rtmp[e];
        int d = (int)(r & 63u);
        int rank = atomicAdd(&cur2[d], 1);               // LDS atomic
        recs[exclL[d] + rank] = r >> 6;
    }
}

// ---- Phase A: gather-GEMM, REL-INTERLEAVED block map for X locality ----
// b < 16*PSTRIDE: rel = b&15, pos = b>>4  (concurrent blocks share X region)
// else: self rel, pos = b - 16*PSTRIDE
__global__ __launch_bounds__(256) void k_phaseA(
    const unsigned short* __restrict__ x, const unsigned short* __restrict__ Wb,
    const int* __restrict__ srcOf, const int* __restrict__ relB,
    unsigned short* __restrict__ T, int capRows)
{
    __shared__ unsigned short Xs[64 * 136];
    __shared__ unsigned short Cs[64 * 136];
    __shared__ int sSrc[64];
    __shared__ int sRB[17];

    int tid = threadIdx.x;
    if (tid < 17) sRB[tid] = relB[tid];
    __syncthreads();

    int b = blockIdx.x;
    int r, row0;
    int rtot = sRB[16];
    if (b < 16 * PSTRIDE) {
        r = b & 15;
        row0 = sRB[r] + ((b >> 4) << 6);
        if (row0 >= sRB[r + 1]) return;                  // idle slot
    } else {
        r = 16;
        row0 = rtot + ((b - 16 * PSTRIDE) << 6);
        if (row0 >= rtot + N_PAD) return;
    }
    if (row0 + 64 > capRows) return;                     // ws capacity guard

    if (tid < 64) sSrc[tid] = (r == 16) ? (row0 - rtot + tid) : srcOf[row0 + tid];
    __syncthreads();

    {
        int row = tid >> 2, c0 = tid & 3;
        const uint4* xp = (const uint4*)(x + (size_t)sSrc[row] * DIM);
        uint4* lp = (uint4*)(&Xs[row * 136]);
        #pragma unroll
        for (int i = 0; i < 4; ++i) lp[c0 + 4 * i] = xp[c0 + 4 * i];
    }
    __syncthreads();

    int w = tid >> 6, l = tid & 63;
    int nl = l & 15, q = l >> 4;

    bf16x8 Bf[2][4];
    const unsigned short* wr = Wb + r * 16384;
    #pragma unroll
    for (int nt = 0; nt < 2; ++nt) {
        int n = w * 32 + nt * 16 + nl;
        #pragma unroll
        for (int kc = 0; kc < 4; ++kc)
            Bf[nt][kc] = *(const bf16x8*)(wr + n * 128 + kc * 32 + q * 8);
    }
    #pragma unroll
    for (int m = 0; m < 4; ++m) {
        f32x4 a0 = {0.f,0.f,0.f,0.f}, a1 = {0.f,0.f,0.f,0.f};
        #pragma unroll
        for (int kc = 0; kc < 4; ++kc) {
            bf16x8 a = *(const bf16x8*)(&Xs[(m * 16 + nl) * 136 + kc * 32 + q * 8]);
            a0 = __builtin_amdgcn_mfma_f32_16x16x32_bf16(a, Bf[0][kc], a0, 0, 0, 0);
            a1 = __builtin_amdgcn_mfma_f32_16x16x32_bf16(a, Bf[1][kc], a1, 0, 0, 0);
        }
        int col = w * 32 + nl;
        #pragma unroll
        for (int reg = 0; reg < 4; ++reg) {
            int row = m * 16 + q * 4 + reg;
            Cs[row * 136 + col]      = f2bf(a0[reg]);
            Cs[row * 136 + col + 16] = f2bf(a1[reg]);
        }
    }
    __syncthreads();
    {
        unsigned short* Tb = T + (size_t)row0 * DIM;
        #pragma unroll
        for (int it = 0; it < 4; ++it) {
            int c = tid + it * 256;
            int row = c >> 4, k8 = c & 15;
            uint4 vv = *(const uint4*)(&Cs[row * 136 + k8 * 8]);
            *(uint4*)(Tb + row * DIM + k8 * 8) = vv;
        }
    }
}

// ---- Phase B: unchanged ----
__global__ __launch_bounds__(256) void k_phaseB(
    const unsigned short* __restrict__ T, const unsigned int* __restrict__ recs,
    const int* __restrict__ offsD, const int* __restrict__ relB,
    const float* __restrict__ bias,
    unsigned short* __restrict__ aggOut, int relu)
{
    __shared__ int sOffs[33];
    __shared__ float sBias[128];
    __shared__ int sSelf;
    int tid = threadIdx.x;
    int v0 = blockIdx.x * 32;
    if (tid < 33) sOffs[tid] = offsD[v0 + tid];
    if (tid == 40) sSelf = relB[16];
    if (tid >= 64 && tid < 96) ((float4*)sBias)[tid - 64] = ((const float4*)bias)[tid - 64];
    __syncthreads();

    int g = tid >> 3, s = tid & 7;
    int dst = v0 + g;
    float qa[16];
    #pragma unroll
    for (int i = 0; i < 16; ++i) qa[i] = sBias[s * 16 + i];

    int beg = sOffs[g], end = sOffs[g + 1];
    int e = beg;
    for (; e + 3 < end; e += 4) {
        unsigned int c0 = recs[e], c1 = recs[e+1], c2 = recs[e+2], c3 = recs[e+3];
        const uint4* t0 = (const uint4*)(T + (size_t)c0 * DIM + s * 16);
        const uint4* t1 = (const uint4*)(T + (size_t)c1 * DIM + s * 16);
        const uint4* t2 = (const uint4*)(T + (size_t)c2 * DIM + s * 16);
        const uint4* t3 = (const uint4*)(T + (size_t)c3 * DIM + s * 16);
        uint4 a0 = t0[0], a1 = t0[1], b0 = t1[0], b1 = t1[1];
        uint4 cc0 = t2[0], cc1 = t2[1], d0 = t3[0], d1 = t3[1];
        accum8(qa, a0); accum8(qa + 8, a1);
        accum8(qa, b0); accum8(qa + 8, b1);
        accum8(qa, cc0); accum8(qa + 8, cc1);
        accum8(qa, d0); accum8(qa + 8, d1);
    }
    for (; e < end; ++e) {
        unsigned int c = recs[e];
        const uint4* tp = (const uint4*)(T + (size_t)c * DIM + s * 16);
        uint4 u0 = tp[0], u1 = tp[1];
        accum8(qa, u0); accum8(qa + 8, u1);
    }
    {
        const uint4* tp = (const uint4*)(T + (size_t)(sSelf + dst) * DIM + s * 16);
        uint4 u0 = tp[0], u1 = tp[1];
        accum8(qa, u0); accum8(qa + 8, u1);
    }

    if (relu) {
        #pragma unroll
        for (int i = 0; i < 16; ++i) qa[i] = fmaxf(qa[i], 0.f);
    }
    pack16(qa, aggOut + (size_t)dst * DIM + s * 16);
}

__global__ void k_pool(const unsigned short* __restrict__ agg2, const int* __restrict__ gids,
                       float* __restrict__ hg_sum, int* __restrict__ cnt)
{
    int d  = threadIdx.x;
    int n0 = blockIdx.x * POOL_CH;
    int nend = min(n0 + POOL_CH, N_NODES);
    if (n0 >= N_NODES) return;
    int curg = gids[n0];
    float run = 0.f;
    for (int n = n0; n < nend; ++n) {
        int g = gids[n];
        if (g != curg) { atomAddF(&hg_sum[curg*DIM + d], run); run = 0.f; curg = g; }
        run += fmaxf(bf2f((unsigned int)agg2[n*DIM + d]), 0.f);
    }
    atomAddF(&hg_sum[curg*DIM + d], run);
    if (d == 0) {
        int cg = gids[n0]; int rl = 0;
        for (int n = n0; n < nend; ++n) {
            int g = gids[n];
            if (g != cg) { atomicAdd(&cnt[cg], rl); rl = 0; cg = g; }
            rl++;
        }
        atomicAdd(&cnt[cg], rl);
    }
}

__global__ __launch_bounds__(256) void k_head(
    const float* __restrict__ hg_sum, const int* __restrict__ cnt,
    const float* __restrict__ Wfc, const float* __restrict__ bfc,
    const float* __restrict__ Wc, const float* __restrict__ bc,
    float* __restrict__ out)
{
    int g = blockIdx.x, t = threadIdx.x;
    __shared__ float hgl[DIM];
    __shared__ float fcl[FC_DIM];
    __shared__ float lg[N_CLASSES];
    if (t < DIM) {
        float c = (float)max(cnt[g], 1);
        hgl[t] = hg_sum[g*DIM + t] / c;
    }
    __syncthreads();
    {
        float sv = bfc[t];
        #pragma unroll 4
        for (int k = 0; k < DIM; ++k) sv += hgl[k] * Wfc[k*FC_DIM + t];
        fcl[t] = fmaxf(sv, 0.f);
    }
    __syncthreads();
    if (t < N_CLASSES) {
        float lgt = bc[t];
        #pragma unroll 4
        for (int k = 0; k < FC_DIM; ++k) lgt += fcl[k] * Wc[k*N_CLASSES + t];
        lg[t] = lgt;
    }
    __syncthreads();
    if (t < N_CLASSES) {
        float m = lg[0];
        #pragma unroll
        for (int c = 1; c < N_CLASSES; ++c) m = fmaxf(m, lg[c]);
        float sden = 0.f;
        #pragma unroll
        for (int c = 0; c < N_CLASSES; ++c) sden += expf(lg[c] - m);
        out[g*N_CLASSES + t] = expf(lg[t] - m) / sden;
    }
}

extern "C" void kernel_launch(void* const* d_in, const int* in_sizes, int n_in,
                              void* d_out, int out_size, void* d_ws, size_t ws_size,
                              hipStream_t stream)
{
    const float* h   = (const float*)d_in[0];
    const int*   src = (const int*)d_in[1];
    const int*   dst = (const int*)d_in[2];
    const int*   rel = (const int*)d_in[3];
    const int*   gid = (const int*)d_in[4];
    const float* W1  = (const float*)d_in[5];
    const float* Ws1 = (const float*)d_in[6];
    const float* b1  = (const float*)d_in[7];
    const float* W2  = (const float*)d_in[8];
    const float* Ws2 = (const float*)d_in[9];
    const float* b2  = (const float*)d_in[10];
    const float* Wfc = (const float*)d_in[11];
    const float* bfc = (const float*)d_in[12];
    const float* Wc  = (const float*)d_in[13];
    const float* bc  = (const float*)d_in[14];
    float* out = (float*)d_out;

    char* ws = (char*)d_ws;
    unsigned char* mark = (unsigned char*)(ws + WS_MARK);
    float* hgsum = (float*)(ws + WS_HG);
    int*   cnt   = (int*)(ws + WS_CNT);
    int*   srcOf = (int*)(ws + WS_SRCOF);
    int*   blkH  = (int*)(ws + WS_BLKH);
    int*   cOffs = (int*)(ws + WS_COFS);
    int*   partP = (int*)(ws + WS_PARTP);
    int*   blkB  = (int*)(ws + WS_BLKB);
    int*   relB  = (int*)(ws + WS_RELB);
    int*   cidMap= (int*)(ws + WS_CIDMAP);
    unsigned int* rtmp = (unsigned int*)(ws + WS_RTMP);
    unsigned int* recs = (unsigned int*)(ws + WS_RECS);
    int*   offsD = (int*)(ws + WS_OFFSD);
    unsigned short* x1  = (unsigned short*)(ws + WS_X1);
    unsigned short* x2  = (unsigned short*)(ws + WS_X2);
    unsigned short* agg = (unsigned short*)(ws + WS_AGG);
    unsigned short* Wb  = (unsigned short*)(ws + WS_WB);
    unsigned short* T   = (unsigned short*)(ws + WS_T);

    int capRows = MAXBLK_A * 64;
    if (ws_size > (size_t)WS_T) {
        long long cr = (long long)((ws_size - WS_T) / 256);
        if (cr < capRows) capRows = (int)cr;
    }

    hipMemsetAsync(mark, 0, MEMSET_SZ, stream);    // mark+hg+cnt+srcOf

    k_convXW<<<XW_TOTAL / 256, 256, 0, stream>>>(h, x1, W1, Ws1, W2, Ws2, Wb);
    k_h1<<<NCH, 256, 0, stream>>>(src, dst, rel, mark, blkH);

    k_scanPA<<<NBLK_PP, 256, 0, stream>>>((const unsigned int*)mark, partP);
    k_scans<<<2, 1024, 0, stream>>>(blkH, cOffs, partP, blkB, relB);
    k_scanPC<<<NBLK_PP, 256, 0, stream>>>((const unsigned int*)mark, blkB, cidMap, srcOf);

    k_scat1<<<NCH, 256, 0, stream>>>(src, dst, rel, cidMap, blkH, rtmp);
    k_p2<<<NCOARSE, 256, 0, stream>>>(rtmp, cOffs, recs, offsD);

    k_phaseA<<<MAXBLK_A, 256, 0, stream>>>(x1, Wb, srcOf, relB, T, capRows);
    k_phaseB<<<N_PAD / 32, 256, 0, stream>>>(T, recs, offsD, relB, b1, x2, 1);
    k_phaseA<<<MAXBLK_A, 256, 0, stream>>>(x2, Wb + 17 * 16384, srcOf, relB, T, capRows);
    k_phaseB<<<N_PAD / 32, 256, 0, stream>>>(T, recs, offsD, relB, b2, agg, 0);

    k_pool<<<(N_PAD + POOL_CH - 1) / POOL_CH, 128, 0, stream>>>(agg, gid, hgsum, cnt);
    k_head<<<N_GRAPHS, 256, 0, stream>>>(hgsum, cnt, Wfc, bfc, Wc, bc, out);
}